// Round 1
// baseline (7570.329 us; speedup 1.0000x reference)
//
#include <hip/hip_runtime.h>

typedef __bf16 bf16x8 __attribute__((ext_vector_type(8)));
typedef float f32x4 __attribute__((ext_vector_type(4)));
typedef unsigned short u16;

#define NT 50
#define NB 1024
#define DET 600
#define DP 608        // padded deter/mlp dim (19*32)
#define GN 1920       // padded 3*DP rounded to 128
#define OUTW 792

__device__ __forceinline__ u16 f2bf(float f) {
  unsigned u = __float_as_uint(f);
  u += 0x7FFFu + ((u >> 16) & 1u);
  return (u16)(u >> 16);
}
__device__ __forceinline__ float eluf(float x) { return x > 0.f ? x : expm1f(x); }
__device__ __forceinline__ float sigm(float x) { return 1.f / (1.f + expf(-x)); }
__device__ __forceinline__ float softplusf(float x) {
  return fmaxf(x, 0.f) + log1pf(expf(-fabsf(x)));
}

struct GemmZ {
  const u16* A;       // bf16 A, row stride DP, used for k < ksplit
  const float* Af;    // f32 concat tail (k >= ksplit), row stride fld
  const u16* B;       // bf16 B [N'][K], row stride K
  int K;
  const float* bias;  // MODE 1 only
  void* C;
};

// C[M,N'] = A[M,K] @ B[N',K]^T. block 256 thr = 4 waves (2x2), wave tile 64x64,
// block tile 128x128, BK=32. MODE 0: raw f32 store (ldc). MODE 1: elu(x+bias) -> bf16, stride DP.
template<int MODE>
__global__ __launch_bounds__(256) void gemm_bt(GemmZ g0, GemmZ g1, int ksplit, int fld, int ldc)
{
  GemmZ g = (blockIdx.z == 0) ? g0 : g1;
  const int tid = threadIdx.x;
  const int lane = tid & 63, w = tid >> 6;
  const int wr = w >> 1, wc = w & 1;
  const int m0 = blockIdx.y * 128, n0 = blockIdx.x * 128;
  __shared__ u16 lA[128 * 32];
  __shared__ u16 lB[128 * 32];
  f32x4 acc[4][4] = {};
  const int r16 = lane & 15, k8 = (lane >> 4) * 8;

  for (int kc = 0; kc < g.K; kc += 32) {
#pragma unroll
    for (int it = 0; it < 2; ++it) {
      int idx = tid + it * 256;
      int row = idx >> 2, seg = idx & 3;
      int kk = kc + seg * 8;
      int4 av;
      if (kk >= ksplit) {
        const float* fp = g.Af + (size_t)(m0 + row) * fld + (kk - ksplit);
        float4 f0 = *(const float4*)fp;
        float4 f1 = *(const float4*)(fp + 4);
        union { u16 h[8]; int4 v; } cv;
        cv.h[0] = f2bf(f0.x); cv.h[1] = f2bf(f0.y); cv.h[2] = f2bf(f0.z); cv.h[3] = f2bf(f0.w);
        cv.h[4] = f2bf(f1.x); cv.h[5] = f2bf(f1.y); cv.h[6] = f2bf(f1.z); cv.h[7] = f2bf(f1.w);
        av = cv.v;
      } else {
        av = *(const int4*)(g.A + (size_t)(m0 + row) * DP + kk);
      }
      *(int4*)&lA[row * 32 + seg * 8] = av;
      int4 bv = *(const int4*)(g.B + (size_t)(n0 + row) * g.K + kk);
      *(int4*)&lB[row * 32 + seg * 8] = bv;
    }
    __syncthreads();
    bf16x8 fa[4], fb[4];
#pragma unroll
    for (int i = 0; i < 4; i++) fa[i] = *(const bf16x8*)&lA[(wr * 64 + i * 16 + r16) * 32 + k8];
#pragma unroll
    for (int j = 0; j < 4; j++) fb[j] = *(const bf16x8*)&lB[(wc * 64 + j * 16 + r16) * 32 + k8];
#pragma unroll
    for (int i = 0; i < 4; i++)
#pragma unroll
      for (int j = 0; j < 4; j++)
        acc[i][j] = __builtin_amdgcn_mfma_f32_16x16x32_bf16(fa[i], fb[j], acc[i][j], 0, 0, 0);
    __syncthreads();
  }

  if (MODE == 0) {
    float* C = (float*)g.C;
#pragma unroll
    for (int i = 0; i < 4; i++) {
      int m = m0 + wr * 64 + i * 16 + (lane >> 4) * 4;
#pragma unroll
      for (int j = 0; j < 4; j++) {
        int n = n0 + wc * 64 + j * 16 + r16;
#pragma unroll
        for (int r = 0; r < 4; r++)
          C[(size_t)(m + r) * ldc + n] = acc[i][j][r];
      }
    }
  } else {
    u16* C = (u16*)g.C;
#pragma unroll
    for (int i = 0; i < 4; i++) {
      int m = m0 + wr * 64 + i * 16 + (lane >> 4) * 4;
#pragma unroll
      for (int j = 0; j < 4; j++) {
        int n = n0 + wc * 64 + j * 16 + r16;
        if (n < DP) {
          float b = (n < DET) ? g.bias[n] : 0.f;
#pragma unroll
          for (int r = 0; r < 4; r++) {
            float v = acc[i][j][r] + b;
            C[(size_t)(m + r) * DP + n] = f2bf(eluf(v));
          }
        }
      }
    }
  }
}

__global__ __launch_bounds__(256) void gates_k(const float* gi, const float* gh,
    const float* b_ih, const float* b_hh, const float* dprev, int dstride,
    float* out_t, u16* hb)
{
  int idx = blockIdx.x * 256 + threadIdx.x;
  if (idx >= NB * DP) return;
  int m = idx / DP, n = idx - m * DP;
  if (n >= DET) { hb[idx] = 0; return; }
  size_t base = (size_t)m * GN;
  float ir = gi[base + n]        + b_ih[n];
  float iz = gi[base + 608 + n]  + b_ih[600 + n];
  float inn = gi[base + 1216 + n] + b_ih[1200 + n];
  float hr = gh[base + n]        + b_hh[n];
  float hz = gh[base + 608 + n]  + b_hh[600 + n];
  float hn = gh[base + 1216 + n] + b_hh[1200 + n];
  float r = sigm(ir + hr);
  float z = sigm(iz + hz);
  float nn = tanhf(inn + r * hn);
  float h = (1.f - z) * nn + z * dprev[(size_t)m * dstride + n];
  out_t[(size_t)m * OUTW + n] = h;
  hb[idx] = f2bf(h);
}

// 32 blocks x 256 thr. block covers 32 rows. waves: 0: p rows0-15, 1: p rows16-31,
// 2: q rows0-15, 3: q rows16-31. Each wave: 16 rows x 64 cols (mu|std-pre) via 4 MFMA accums.
__global__ __launch_bounds__(256) void heads2_k(const u16* phb, const u16* qhb,
    const u16* Wp2p, const u16* Wq2p, const float* bp2, const float* bq2,
    const float* np_t, const float* nq_t, float* out_t, float* stocbuf)
{
  int tid = threadIdx.x, lane = tid & 63, w = tid >> 6;
  int isq = w >> 1;
  int m0 = blockIdx.x * 32 + (w & 1) * 16;
  const u16* Ap = isq ? qhb : phb;
  const u16* Bp = isq ? Wq2p : Wp2p;
  const float* bias = isq ? bq2 : bp2;
  const float* noise = isq ? nq_t : np_t;
  int r16 = lane & 15, k8 = (lane >> 4) * 8;
  f32x4 acc[4] = {};
  for (int kc = 0; kc < DP; kc += 32) {
    bf16x8 fa = *(const bf16x8*)&Ap[(size_t)(m0 + r16) * DP + kc + k8];
#pragma unroll
    for (int j = 0; j < 4; j++) {
      bf16x8 fb = *(const bf16x8*)&Bp[(size_t)(j * 16 + r16) * DP + kc + k8];
      acc[j] = __builtin_amdgcn_mfma_f32_16x16x32_bf16(fa, fb, acc[j], 0, 0, 0);
    }
  }
  int ob = isq ? 696 : 600;
#pragma unroll
  for (int j = 0; j < 2; j++) {
    int c = j * 16 + r16;
#pragma unroll
    for (int r = 0; r < 4; r++) {
      int m = m0 + (lane >> 4) * 4 + r;
      float mu = acc[j][r] + bias[c];
      float sp = acc[j + 2][r] + bias[32 + c];
      float sd = softplusf(sp) + 0.1f;
      float st = mu + sd * noise[(size_t)m * 32 + c];
      float* op = out_t + (size_t)m * OUTW + ob;
      op[c] = mu;
      op[32 + c] = sd;
      op[64 + c] = st;
      if (isq) stocbuf[m * 32 + c] = st;
    }
  }
}

__global__ __launch_bounds__(256) void xnext_k(const float* stoc, const float* a_t,
    const float* nt_t, const float* W_in, const float* b_in, u16* xb)
{
  int idx = blockIdx.x * 256 + threadIdx.x;
  if (idx >= NB * DP) return;
  int m = idx / DP, n = idx - m * DP;
  if (n >= DET) { xb[idx] = 0; return; }
  float ntv = nt_t[m];
  const float* wr = W_in + n * 38;
  const float* s = stoc + m * 32;
  float a = b_in[n];
#pragma unroll
  for (int k = 0; k < 32; k++) a += s[k] * ntv * wr[k];
  const float* av = a_t + m * 6;
#pragma unroll
  for (int k = 0; k < 6; k++) a += av[k] * wr[32 + k];
  xb[idx] = f2bf(eluf(a));
}

__global__ __launch_bounds__(256) void wconv_k(const float* src, int srows, int scols, int sstride,
    u16* dst, int drows, int dstride, int c0, int cw)
{
  int idx = blockIdx.x * 256 + threadIdx.x;
  if (idx >= drows * cw) return;
  int r = idx / cw, c = idx - r * cw;
  float v = (r < srows && c < scols) ? src[(size_t)r * sstride + c] : 0.f;
  dst[(size_t)r * dstride + c0 + c] = f2bf(v);
}

extern "C" void kernel_launch(void* const* d_in, const int* in_sizes, int n_in,
                              void* d_out, int out_size, void* d_ws, size_t ws_size,
                              hipStream_t stream)
{
  const float* actions   = (const float*)d_in[0];
  const float* nonterm   = (const float*)d_in[1];
  const float* emb       = (const float*)d_in[2];
  const float* noise_p   = (const float*)d_in[3];
  const float* noise_q   = (const float*)d_in[4];
  const float* init_deter = (const float*)d_in[5];
  const float* init_stoc  = (const float*)d_in[6];
  const float* W_in = (const float*)d_in[7];
  const float* b_in = (const float*)d_in[8];
  const float* W_ih = (const float*)d_in[9];
  const float* b_ih = (const float*)d_in[10];
  const float* W_hh = (const float*)d_in[11];
  const float* b_hh = (const float*)d_in[12];
  const float* Wp1 = (const float*)d_in[13];
  const float* bp1 = (const float*)d_in[14];
  const float* Wp2 = (const float*)d_in[15];
  const float* bp2 = (const float*)d_in[16];
  const float* Wq1 = (const float*)d_in[17];
  const float* bq1 = (const float*)d_in[18];
  const float* Wq2 = (const float*)d_in[19];
  const float* bq2 = (const float*)d_in[20];
  float* out = (float*)d_out;

  char* w = (char*)d_ws;
  size_t o = 0;
  auto alloc = [&](size_t bytes) -> char* {
    char* p = w + o;
    o = (o + bytes + 255) & ~(size_t)255;
    return p;
  };
  u16* Wihp = (u16*)alloc(1920ull * 608 * 2);
  u16* Whhp = (u16*)alloc(1920ull * 608 * 2);
  u16* Wp1p = (u16*)alloc(640ull * 608 * 2);
  u16* Wq1p = (u16*)alloc(640ull * 1632 * 2);
  u16* Wp2p = (u16*)alloc(64ull * 608 * 2);
  u16* Wq2p = (u16*)alloc(64ull * 608 * 2);
  u16* xb  = (u16*)alloc(1024ull * 608 * 2);
  u16* hb  = (u16*)alloc(1024ull * 608 * 2);
  u16* phb = (u16*)alloc(1024ull * 608 * 2);
  u16* qhb = (u16*)alloc(1024ull * 608 * 2);
  float* gi = (float*)alloc(1024ull * 1920 * 4);
  float* gh = (float*)alloc(1024ull * 1920 * 4);
  float* stocbuf = (float*)alloc(1024ull * 32 * 4);
  if (o > ws_size) return;  // workspace insufficient; bail rather than corrupt

  auto wcl = [&](const float* src, int sr, int sc, int ss, u16* dst, int dr, int ds, int c0, int cw) {
    int n = dr * cw;
    wconv_k<<<(n + 255) / 256, 256, 0, stream>>>(src, sr, sc, ss, dst, dr, ds, c0, cw);
  };
  // GRU weights: 3 gate sections each padded [600,600] -> [608,608] (last section pads rows to 1920)
  for (int s = 0; s < 3; s++) {
    wcl(W_ih + (size_t)s * 600 * 600, 600, 600, 600, Wihp + (size_t)s * 608 * 608, s == 2 ? 704 : 608, 608, 0, 608);
    wcl(W_hh + (size_t)s * 600 * 600, 600, 600, 600, Whhp + (size_t)s * 608 * 608, s == 2 ? 704 : 608, 608, 0, 608);
  }
  wcl(Wp1, 600, 600, 600, Wp1p, 640, 608, 0, 608);
  wcl(Wq1, 600, 600, 1624, Wq1p, 640, 1632, 0, 608);        // h-part cols
  wcl(Wq1 + 600, 600, 1024, 1624, Wq1p, 640, 1632, 608, 1024); // emb-part cols
  wcl(Wp2, 64, 600, 600, Wp2p, 64, 608, 0, 608);
  wcl(Wq2, 64, 600, 600, Wq2p, 64, 608, 0, 608);
  wcl(init_deter, 1024, 600, 600, hb, 1024, 608, 0, 608);   // h_{-1} -> bf16 padded

  // x_0 = elu([init_stoc*nt_0, a_0] @ W_in^T + b_in)
  xnext_k<<<2432, 256, 0, stream>>>(init_stoc, actions, nonterm, W_in, b_in, xb);

  for (int t = 0; t < NT; t++) {
    float* out_t = out + (size_t)t * NB * OUTW;

    GemmZ z0 = { xb, nullptr, Wihp, 608, nullptr, gi };
    GemmZ z1 = { hb, nullptr, Whhp, 608, nullptr, gh };
    gemm_bt<0><<<dim3(15, 8, 2), 256, 0, stream>>>(z0, z1, 608, 0, GN);

    const float* dprev = (t == 0) ? init_deter : out + (size_t)(t - 1) * NB * OUTW;
    int dstr = (t == 0) ? 600 : OUTW;
    gates_k<<<2432, 256, 0, stream>>>(gi, gh, b_ih, b_hh, dprev, dstr, out_t, hb);

    GemmZ h0 = { hb, nullptr, Wp1p, 608, bp1, phb };
    GemmZ h1 = { hb, emb + (size_t)t * NB * 1024, Wq1p, 1632, bq1, qhb };
    gemm_bt<1><<<dim3(5, 8, 2), 256, 0, stream>>>(h0, h1, 608, 1024, 0);

    heads2_k<<<32, 256, 0, stream>>>(phb, qhb, Wp2p, Wq2p, bp2, bq2,
        noise_p + (size_t)t * NB * 32, noise_q + (size_t)t * NB * 32, out_t, stocbuf);

    if (t + 1 < NT)
      xnext_k<<<2432, 256, 0, stream>>>(stocbuf, actions + (size_t)(t + 1) * NB * 6,
          nonterm + (size_t)(t + 1) * NB, W_in, b_in, xb);
  }
}

// Round 3
// 4607.107 us; speedup vs baseline: 1.6432x; 1.6432x over previous
//
#include <hip/hip_runtime.h>

typedef __bf16 bf16x8 __attribute__((ext_vector_type(8)));
typedef float f32x4 __attribute__((ext_vector_type(4)));
typedef unsigned short u16;
typedef unsigned int u32;
typedef unsigned long long u64;

#define NT 50
#define NB 1024
#define DET 600
#define DP 608        // padded 600 -> 19*32
#define NP 640        // padded 600 -> 5*128 (N dim of weight tiles)
#define EMB 1024
#define OUTW 792

__device__ __forceinline__ u16 f2bf(float f) {
  unsigned u = __float_as_uint(f);
  u += 0x7FFFu + ((u >> 16) & 1u);
  return (u16)(u >> 16);
}
__device__ __forceinline__ float bf2f(u16 h) { return __uint_as_float(((unsigned)h) << 16); }
__device__ __forceinline__ float eluf(float x) { return x > 0.f ? x : expm1f(x); }
__device__ __forceinline__ float sigm(float x) { return 1.f / (1.f + expf(-x)); }
__device__ __forceinline__ float softplusf(float x) {
  return fmaxf(x, 0.f) + log1pf(expf(-fabsf(x)));
}

// async global->LDS, 16B per lane. LDS dest = wave-uniform base + lane*16.
__device__ __forceinline__ void gll16(const void* g, void* l) {
  __builtin_amdgcn_global_load_lds(
      (const __attribute__((address_space(1))) u32*)g,
      (__attribute__((address_space(3))) u32*)l, 16, 0, 0);
}

// Swizzled chunk layout for [rows][32] bf16 tiles staged as 16B chunks.
// chunk S holds global (row = S>>2, k8 = ((S&3) - ((S>>3)&3)) & 3).
// reader for (row,k8) uses S = row*4 + ((k8 + (row>>1)) & 3)  -> 2-way banks (free).

// ---------------- fused GRU: gi/gh 6-section GEMM + gate math -----------------
struct GruP {
  const u16* xb; const u16* hb; const u16* W6;
  const float* b_ih; const float* b_hh;
  const float* dprev; int dstride;
  float* out_t; u16* hbn;
};

__global__ __launch_bounds__(256, 2) void gru_k(GruP p)
{
  __shared__ u16 lds[2][8][64 * 32];   // 64 KiB: tiles {xb, hb, W6[0..5]}
  const int tid = threadIdx.x;
  const int lane = tid & 63, w = tid >> 6;
  const int wr = w >> 1, wc = w & 1;
  const int m0 = blockIdx.y * 64, n0 = blockIdx.x * 64;
  const int r16 = lane & 15, k8g = lane >> 4;
  f32x4 acc[6][2][2] = {};

  const int srow = tid >> 2;
  const int sk8 = ((tid & 3) - ((tid >> 3) & 3)) & 3;
  const u16* ax = p.xb + (size_t)(m0 + srow) * DP + sk8 * 8;
  const u16* ah = p.hb + (size_t)(m0 + srow) * DP + sk8 * 8;
  const u16* bw[6];
#pragma unroll
  for (int s = 0; s < 6; s++)
    bw[s] = p.W6 + (size_t)s * NP * DP + (size_t)(n0 + srow) * DP + sk8 * 8;
  const int lo = w * 1024;  // this wave's 64-chunk LDS byte offset within a tile

  auto stage = [&](int buf, int kc) {
    gll16(ax + kc, (char*)lds[buf][0] + lo);
    gll16(ah + kc, (char*)lds[buf][1] + lo);
#pragma unroll
    for (int s = 0; s < 6; s++) gll16(bw[s] + kc, (char*)lds[buf][2 + s] + lo);
  };
  auto compute = [&](int buf) {
    bf16x8 ax_[2], ah_[2];
#pragma unroll
    for (int i = 0; i < 2; i++) {
      int row = wr * 32 + i * 16 + r16;
      int S = row * 4 + ((k8g + (row >> 1)) & 3);
      ax_[i] = *(const bf16x8*)((const char*)lds[buf][0] + S * 16);
      ah_[i] = *(const bf16x8*)((const char*)lds[buf][1] + S * 16);
    }
#pragma unroll
    for (int s = 0; s < 6; s++) {
#pragma unroll
      for (int j = 0; j < 2; j++) {
        int row = wc * 32 + j * 16 + r16;
        int S = row * 4 + ((k8g + (row >> 1)) & 3);
        bf16x8 b = *(const bf16x8*)((const char*)lds[buf][2 + s] + S * 16);
#pragma unroll
        for (int i = 0; i < 2; i++)
          acc[s][i][j] = __builtin_amdgcn_mfma_f32_16x16x32_bf16(
              (s < 3) ? ax_[i] : ah_[i], b, acc[s][i][j], 0, 0, 0);
      }
    }
  };

  stage(0, 0);
  __syncthreads();
  for (int it = 0; it < 19; ++it) {
    if (it + 1 < 19) stage((it + 1) & 1, (it + 1) * 32);
    compute(it & 1);
    __syncthreads();
  }

#pragma unroll
  for (int j = 0; j < 2; j++) {
    int n = n0 + wc * 32 + j * 16 + r16;
    if (n >= DET) {
      if (n < DP) {
#pragma unroll
        for (int i = 0; i < 2; i++) {
          int mb = m0 + wr * 32 + i * 16 + k8g * 4;
#pragma unroll
          for (int r = 0; r < 4; r++) p.hbn[(size_t)(mb + r) * DP + n] = 0;
        }
      }
      continue;
    }
    float bihr = p.b_ih[n], bihz = p.b_ih[600 + n], bihn = p.b_ih[1200 + n];
    float bhhr = p.b_hh[n], bhhz = p.b_hh[600 + n], bhhn = p.b_hh[1200 + n];
#pragma unroll
    for (int i = 0; i < 2; i++) {
      int mb = m0 + wr * 32 + i * 16 + k8g * 4;
#pragma unroll
      for (int r = 0; r < 4; r++) {
        int m = mb + r;
        float rg = sigm(acc[0][i][j][r] + bihr + acc[3][i][j][r] + bhhr);
        float zg = sigm(acc[1][i][j][r] + bihz + acc[4][i][j][r] + bhhz);
        float ng = tanhf(acc[2][i][j][r] + bihn + rg * (acc[5][i][j][r] + bhhn));
        float h = (1.f - zg) * ng + zg * p.dprev[(size_t)m * p.dstride + n];
        p.out_t[(size_t)m * OUTW + n] = h;
        p.hbn[(size_t)m * DP + n] = f2bf(h);
      }
    }
  }
}

// ---------------- pipelined GEMM: C = act(A[M,K] @ B[N,K]^T + bias + Cadd) ----
struct GemmZ {
  const u16* A; int lda;
  const u16* A2; int lda2;   // K-tail source (k >= ksplit)
  int ksplit;
  const u16* B; int ldb;
  int K;
  const float* bias;         // nullable (applied n < DET)
  const u16* Cadd; int ldadd; // nullable bf16 addend (pre-activation)
  u16* C; int ldc;
  int mode;                  // 1: elu -> bf16, store n < DP ; 2: raw bf16, store n < ldc
};

__global__ __launch_bounds__(256, 2) void gemmP(GemmZ g0, GemmZ g1)
{
  GemmZ g = blockIdx.z ? g1 : g0;
  __shared__ u16 lA[2][128 * 32];
  __shared__ u16 lB[2][128 * 32];
  const int tid = threadIdx.x, lane = tid & 63, w = tid >> 6;
  const int wr = w >> 1, wc = w & 1;
  const size_t m0 = (size_t)blockIdx.y * 128;
  const int n0 = blockIdx.x * 128;
  const int r16 = lane & 15, k8g = lane >> 4;
  f32x4 acc[4][4] = {};

  const int S0 = tid, S1 = tid + 256;
  const int ar0 = S0 >> 2, ak0 = (((S0 & 3) - ((S0 >> 3) & 3)) & 3) * 8;
  const int ar1 = S1 >> 2, ak1 = (((S1 & 3) - ((S1 >> 3) & 3)) & 3) * 8;
  const int lo = w * 1024;
  const int niter = g.K / 32;

  auto stage = [&](int buf, int kc) {
    {
      int kk = kc + ak0;
      const u16* s = (kk < g.ksplit) ? g.A + (m0 + ar0) * (size_t)g.lda + kk
                                     : g.A2 + (m0 + ar0) * (size_t)g.lda2 + (kk - g.ksplit);
      gll16(s, (char*)lA[buf] + lo);
    }
    {
      int kk = kc + ak1;
      const u16* s = (kk < g.ksplit) ? g.A + (m0 + ar1) * (size_t)g.lda + kk
                                     : g.A2 + (m0 + ar1) * (size_t)g.lda2 + (kk - g.ksplit);
      gll16(s, (char*)lA[buf] + 4096 + lo);
    }
    gll16(g.B + (size_t)(n0 + ar0) * g.ldb + kc + ak0, (char*)lB[buf] + lo);
    gll16(g.B + (size_t)(n0 + ar1) * g.ldb + kc + ak1, (char*)lB[buf] + 4096 + lo);
  };
  auto compute = [&](int buf) {
    bf16x8 fa[4], fb[4];
#pragma unroll
    for (int i = 0; i < 4; i++) {
      int row = wr * 64 + i * 16 + r16;
      int S = row * 4 + ((k8g + (row >> 1)) & 3);
      fa[i] = *(const bf16x8*)((const char*)lA[buf] + S * 16);
    }
#pragma unroll
    for (int j = 0; j < 4; j++) {
      int row = wc * 64 + j * 16 + r16;
      int S = row * 4 + ((k8g + (row >> 1)) & 3);
      fb[j] = *(const bf16x8*)((const char*)lB[buf] + S * 16);
    }
#pragma unroll
    for (int i = 0; i < 4; i++)
#pragma unroll
      for (int j = 0; j < 4; j++)
        acc[i][j] = __builtin_amdgcn_mfma_f32_16x16x32_bf16(fa[i], fb[j], acc[i][j], 0, 0, 0);
  };

  stage(0, 0);
  __syncthreads();
  for (int it = 0; it < niter; ++it) {
    if (it + 1 < niter) stage((it + 1) & 1, (it + 1) * 32);
    compute(it & 1);
    __syncthreads();
  }

  if (g.mode == 1) {
#pragma unroll
    for (int i = 0; i < 4; i++) {
      size_t mb = m0 + wr * 64 + i * 16 + k8g * 4;
#pragma unroll
      for (int j = 0; j < 4; j++) {
        int n = n0 + wc * 64 + j * 16 + r16;
        if (n >= DP) continue;
        float b = (n < DET && g.bias) ? g.bias[n] : 0.f;
#pragma unroll
        for (int r = 0; r < 4; r++) {
          float v = acc[i][j][r] + b;
          if (g.Cadd) v += bf2f(g.Cadd[(mb + r) * (size_t)g.ldadd + n]);
          g.C[(mb + r) * (size_t)g.ldc + n] = f2bf(eluf(v));
        }
      }
    }
  } else {
#pragma unroll
    for (int i = 0; i < 4; i++) {
      size_t mb = m0 + wr * 64 + i * 16 + k8g * 4;
#pragma unroll
      for (int j = 0; j < 4; j++) {
        int n = n0 + wc * 64 + j * 16 + r16;
        if (n >= g.ldc) continue;
#pragma unroll
        for (int r = 0; r < 4; r++)
          g.C[(mb + r) * (size_t)g.ldc + n] = f2bf(acc[i][j][r]);
      }
    }
  }
}

// ---------------- heads-2 + sampling + next-x build + x GEMM ------------------
struct H2P {
  const u16* phb; const u16* qhb; const u16* Wp2; const u16* Wq2;
  const float* bp2; const float* bq2;
  const float* np_t; const float* nq_t;
  float* out_t;
  const float* nt_next; const float* act_next;  // null at t = T-1
  const u16* Winp; const float* b_in; u16* xb;
};

__global__ __launch_bounds__(256) void heads2x_k(H2P p)
{
  __shared__ u16 xin[16 * 64];
  __shared__ float red[2][64][16];
  const int tid = threadIdx.x, lane = tid & 63, w = tid >> 6;
  const int m0 = blockIdx.x * 16;
  const int r16 = lane & 15, k8g = lane >> 4;
  const bool donext = p.nt_next != nullptr;

  if (donext) ((u64*)xin)[tid] = 0ull;

  const int mat = w & 1, half = w >> 1;
  const u16* Ap = mat ? p.qhb : p.phb;
  const u16* Bp = mat ? p.Wq2 : p.Wp2;
  f32x4 acc[4] = {};
  const int kb = half ? 320 : 0, ke = half ? 608 : 320;
  for (int kc = kb; kc < ke; kc += 32) {
    bf16x8 fa = *(const bf16x8*)&Ap[(size_t)(m0 + r16) * DP + kc + k8g * 8];
#pragma unroll
    for (int j = 0; j < 4; j++) {
      bf16x8 fb = *(const bf16x8*)&Bp[(size_t)(j * 16 + r16) * DP + kc + k8g * 8];
      acc[j] = __builtin_amdgcn_mfma_f32_16x16x32_bf16(fa, fb, acc[j], 0, 0, 0);
    }
  }
  if (half) {
#pragma unroll
    for (int j = 0; j < 4; j++) *(f32x4*)&red[mat][lane][j * 4] = acc[j];
  }
  __syncthreads();
  if (!half) {
#pragma unroll
    for (int j = 0; j < 4; j++) acc[j] += *(const f32x4*)&red[mat][lane][j * 4];
    const float* bias = mat ? p.bq2 : p.bp2;
    const float* noise = mat ? p.nq_t : p.np_t;
    const int ob = mat ? 696 : 600;
#pragma unroll
    for (int j = 0; j < 2; j++) {
      int c = j * 16 + r16;
      float bmu = bias[c], bsd = bias[32 + c];
#pragma unroll
      for (int r = 0; r < 4; r++) {
        int m = m0 + k8g * 4 + r;
        float mu = acc[j][r] + bmu;
        float sd = softplusf(acc[j + 2][r] + bsd) + 0.1f;
        float st = mu + sd * noise[(size_t)m * 32 + c];
        float* op = p.out_t + (size_t)m * OUTW + ob;
        op[c] = mu; op[32 + c] = sd; op[64 + c] = st;
        if (mat && donext) xin[(m - m0) * 64 + c] = f2bf(st * p.nt_next[m]);
      }
    }
  } else if (donext && mat) {
    // actions: 16 rows x 6 cols = 96 entries, 64 lanes -> 2 per lane
#pragma unroll
    for (int rep = 0; rep < 2; rep++) {
      int idx = lane + rep * 64;
      if (idx < 96) {
        int rr = idx / 6, c = idx - rr * 6;
        xin[rr * 64 + 32 + c] = f2bf(p.act_next[(size_t)(m0 + rr) * 6 + c]);
      }
    }
  }
  if (!donext) return;
  __syncthreads();

  // x_{t+1} tile: [16][640] = elu(xin[16][64] @ Winp[640][64]^T + b_in) -> bf16
  f32x4 xc[10] = {};
  const int nb = w * 160;
#pragma unroll
  for (int kc = 0; kc < 64; kc += 32) {
    bf16x8 fa = *(const bf16x8*)&xin[r16 * 64 + kc + k8g * 8];
#pragma unroll
    for (int j = 0; j < 10; j++) {
      bf16x8 fb = *(const bf16x8*)&p.Winp[(size_t)(nb + j * 16 + r16) * 64 + kc + k8g * 8];
      xc[j] = __builtin_amdgcn_mfma_f32_16x16x32_bf16(fa, fb, xc[j], 0, 0, 0);
    }
  }
#pragma unroll
  for (int j = 0; j < 10; j++) {
    int n = nb + j * 16 + r16;
    if (n >= DP) continue;
#pragma unroll
    for (int r = 0; r < 4; r++) {
      int m = m0 + k8g * 4 + r;
      float v = (n < DET) ? eluf(xc[j][r] + p.b_in[n]) : 0.f;
      p.xb[(size_t)m * DP + n] = f2bf(v);
    }
  }
}

// ---------------- small prolog kernels ---------------------------------------
__global__ void wconv_k(const float* src, int srows, int scols, int sstride,
                        u16* dst, int drows, int dstride, int c0, int cw)
{
  int idx = blockIdx.x * 256 + threadIdx.x;
  if (idx >= drows * cw) return;
  int r = idx / cw, c = idx - r * cw;
  float v = (r < srows && c < scols) ? src[(size_t)r * sstride + c] : 0.f;
  dst[(size_t)r * dstride + c0 + c] = f2bf(v);
}

__global__ void conv8_k(const float* src, u16* dst, int n8)
{
  int i = blockIdx.x * 256 + threadIdx.x;
  if (i >= n8) return;
  const float4* s = (const float4*)(src + (size_t)i * 8);
  float4 f0 = s[0], f1 = s[1];
  union { u16 h[8]; int4 v; } cv;
  cv.h[0] = f2bf(f0.x); cv.h[1] = f2bf(f0.y); cv.h[2] = f2bf(f0.z); cv.h[3] = f2bf(f0.w);
  cv.h[4] = f2bf(f1.x); cv.h[5] = f2bf(f1.y); cv.h[6] = f2bf(f1.z); cv.h[7] = f2bf(f1.w);
  *(int4*)(dst + (size_t)i * 8) = cv.v;
}

__global__ void xin0_k(const float* stoc0, const float* nt0, const float* act0, u16* xing)
{
  int i = blockIdx.x * 256 + threadIdx.x;
  if (i >= NB * 64) return;
  int m = i >> 6, c = i & 63;
  float v = 0.f;
  if (c < 32) v = stoc0[m * 32 + c] * nt0[m];
  else if (c < 38) v = act0[m * 6 + (c - 32)];
  xing[i] = f2bf(v);
}

// ---------------- host ---------------------------------------------------------
extern "C" void kernel_launch(void* const* d_in, const int* in_sizes, int n_in,
                              void* d_out, int out_size, void* d_ws, size_t ws_size,
                              hipStream_t stream)
{
  const float* actions    = (const float*)d_in[0];
  const float* nonterm    = (const float*)d_in[1];
  const float* emb        = (const float*)d_in[2];
  const float* noise_p    = (const float*)d_in[3];
  const float* noise_q    = (const float*)d_in[4];
  const float* init_deter = (const float*)d_in[5];
  const float* init_stoc  = (const float*)d_in[6];
  const float* W_in = (const float*)d_in[7];
  const float* b_in = (const float*)d_in[8];
  const float* W_ih = (const float*)d_in[9];
  const float* b_ih = (const float*)d_in[10];
  const float* W_hh = (const float*)d_in[11];
  const float* b_hh = (const float*)d_in[12];
  const float* Wp1 = (const float*)d_in[13];
  const float* bp1 = (const float*)d_in[14];
  const float* Wp2 = (const float*)d_in[15];
  const float* bp2 = (const float*)d_in[16];
  const float* Wq1 = (const float*)d_in[17];
  const float* bq1 = (const float*)d_in[18];
  const float* Wq2 = (const float*)d_in[19];
  const float* bq2 = (const float*)d_in[20];
  float* out = (float*)d_out;

  char* wsp = (char*)d_ws;
  size_t o = 0;
  auto alloc = [&](size_t b) { char* p = wsp + o; o = (o + b + 255) & ~(size_t)255; return p; };
  u16* W6   = (u16*)alloc(6ull * NP * DP * 2);
  u16* Wp1p = (u16*)alloc((size_t)NP * DP * 2);
  u16* Wq1h = (u16*)alloc((size_t)NP * DP * 2);
  u16* Wq1f = (u16*)alloc((size_t)NP * 1632 * 2);
  u16* Wq1e = (u16*)alloc((size_t)NP * EMB * 2);
  u16* Wp2p = (u16*)alloc(64ull * DP * 2);
  u16* Wq2p = (u16*)alloc(64ull * DP * 2);
  u16* Winp = (u16*)alloc((size_t)NP * 64 * 2);
  u16* xb   = (u16*)alloc((size_t)NB * DP * 2);
  u16* hb0  = (u16*)alloc((size_t)NB * DP * 2);
  u16* hb1  = (u16*)alloc((size_t)NB * DP * 2);
  u16* phb  = (u16*)alloc((size_t)NB * DP * 2);
  u16* qhb  = (u16*)alloc((size_t)NB * DP * 2);
  u16* xing = (u16*)alloc((size_t)NB * 64 * 2);
  u16* embt = (u16*)alloc((size_t)NB * EMB * 2);
  size_t small_o = o;
  u16* embb = (u16*)alloc((size_t)NT * NB * EMB * 2);
  u16* QE   = (u16*)alloc((size_t)NT * NB * NP * 2);
  const bool bigws = (o <= ws_size);
  if (small_o > ws_size) return;

  auto wcl = [&](const float* src, int sr, int sc, int ss, u16* dst, int dr, int ds, int c0, int cw) {
    int n = dr * cw;
    wconv_k<<<(n + 255) / 256, 256, 0, stream>>>(src, sr, sc, ss, dst, dr, ds, c0, cw);
  };
  for (int s = 0; s < 3; s++) {
    wcl(W_ih + (size_t)s * 600 * 600, 600, 600, 600, W6 + (size_t)s * NP * DP, NP, DP, 0, DP);
    wcl(W_hh + (size_t)s * 600 * 600, 600, 600, 600, W6 + (size_t)(3 + s) * NP * DP, NP, DP, 0, DP);
  }
  wcl(Wp1, 600, 600, 600, Wp1p, NP, DP, 0, DP);
  wcl(Wp2, 64, 600, 600, Wp2p, 64, DP, 0, DP);
  wcl(Wq2, 64, 600, 600, Wq2p, 64, DP, 0, DP);
  wcl(W_in, 600, 38, 38, Winp, NP, 64, 0, 64);
  wcl(init_deter, 1024, 600, 600, hb0, 1024, DP, 0, DP);
  if (bigws) {
    wcl(Wq1, 600, 600, 1624, Wq1h, NP, DP, 0, DP);
    wcl(Wq1 + 600, 600, 1024, 1624, Wq1e, NP, EMB, 0, EMB);
    int n8 = NT * NB * EMB / 8;
    conv8_k<<<(n8 + 255) / 256, 256, 0, stream>>>(emb, embb, n8);
    GemmZ gq = { embb, EMB, nullptr, 0, 1024, Wq1e, EMB, 1024,
                 nullptr, nullptr, 0, QE, NP, 2 };
    gemmP<<<dim3(5, 400, 1), 256, 0, stream>>>(gq, gq);
  } else {
    wcl(Wq1, 600, 600, 1624, Wq1f, NP, 1632, 0, DP);
    wcl(Wq1 + 600, 600, 1024, 1624, Wq1f, NP, 1632, DP, EMB);
  }

  xin0_k<<<NB * 64 / 256, 256, 0, stream>>>(init_stoc, nonterm, actions, xing);
  {
    GemmZ gx = { xing, 64, nullptr, 0, 64, Winp, 64, 64, b_in, nullptr, 0, xb, DP, 1 };
    gemmP<<<dim3(5, 8, 1), 256, 0, stream>>>(gx, gx);
  }

  for (int t = 0; t < NT; t++) {
    float* out_t = out + (size_t)t * NB * OUTW;
    u16* hcur = (t & 1) ? hb1 : hb0;
    u16* hnxt = (t & 1) ? hb0 : hb1;
    const float* dprev = (t == 0) ? init_deter : out + (size_t)(t - 1) * NB * OUTW;
    int dstr = (t == 0) ? 600 : OUTW;

    GruP gp = { xb, hcur, W6, b_ih, b_hh, dprev, dstr, out_t, hnxt };
    gru_k<<<dim3(10, 16, 1), 256, 0, stream>>>(gp);

    GemmZ h0 = { hnxt, DP, nullptr, 0, DP, Wp1p, DP, DP, bp1, nullptr, 0, phb, DP, 1 };
    GemmZ h1;
    if (bigws) {
      h1 = GemmZ{ hnxt, DP, nullptr, 0, DP, Wq1h, DP, DP, bq1,
                  QE + (size_t)t * NB * NP, NP, qhb, DP, 1 };
    } else {
      int n8 = NB * EMB / 8;
      conv8_k<<<(n8 + 255) / 256, 256, 0, stream>>>(emb + (size_t)t * NB * EMB, embt, n8);
      h1 = GemmZ{ hnxt, DP, embt, EMB, DP, Wq1f, 1632, 1632, bq1,
                  nullptr, 0, qhb, DP, 1 };
    }
    gemmP<<<dim3(5, 8, 2), 256, 0, stream>>>(h0, h1);

    H2P hp = { phb, qhb, Wp2p, Wq2p, bp2, bq2,
               noise_p + (size_t)t * NB * 32, noise_q + (size_t)t * NB * 32, out_t,
               (t + 1 < NT) ? nonterm + (size_t)(t + 1) * NB : nullptr,
               (t + 1 < NT) ? actions + (size_t)(t + 1) * NB * 6 : nullptr,
               Winp, b_in, xb };
    heads2x_k<<<64, 256, 0, stream>>>(hp);
  }
}